// Round 1
// baseline (5728.333 us; speedup 1.0000x reference)
//
#include <hip/hip_runtime.h>
#include <cstdint>

#define BN_EPS 1e-5f

constexpr int KTOT  = 128;   // K of every GEMM (input feature width)
constexpr int BM    = 128;   // rows per block
constexpr int KSTEP = 32;    // K chunk staged in LDS

// ---------- small prep kernels ----------

__global__ __launch_bounds__(256) void k_deg(const int* __restrict__ dst,
                                             float* __restrict__ deg, int E) {
  int e = blockIdx.x * 256 + threadIdx.x;
  if (e < E) atomicAdd(deg + dst[e], 1.0f);
}

__global__ __launch_bounds__(256) void k_dis(const float* __restrict__ deg,
                                             float* __restrict__ dis, int N) {
  int i = blockIdx.x * 256 + threadIdx.x;
  if (i < N) dis[i] = rsqrtf(deg[i] + 1.0f);
}

__global__ __launch_bounds__(256) void k_coef(const int* __restrict__ src,
                                              const int* __restrict__ dst,
                                              const float* __restrict__ dis,
                                              float* __restrict__ coef, int E) {
  int e = blockIdx.x * 256 + threadIdx.x;
  if (e < E) coef[e] = dis[src[e]] * dis[dst[e]];
}

__global__ __launch_bounds__(256) void k_bnparam(const float* __restrict__ gamma,
                                                 const float* __restrict__ beta,
                                                 const float* __restrict__ mean,
                                                 const float* __restrict__ var,
                                                 float* __restrict__ scale,
                                                 float* __restrict__ shift, int n) {
  int i = blockIdx.x * 256 + threadIdx.x;
  if (i < n) {
    float s = gamma[i] * rsqrtf(var[i] + BN_EPS);
    scale[i] = s;
    shift[i] = beta[i] - mean[i] * s;
  }
}

// ---------- fused GEMM ----------
// out tile: BM x BNC, block 16x16 threads, per-thread 8 x TN register tile.
// APPLY_BN: input h is pre-BN (prev layer agg); apply relu(h*scale+shift) on load.
// FINAL: write only out = acc + bias. Else write t and agg = t*dis^2 + bias.
template <int BNC, int TN, bool APPLY_BN, bool FINAL>
__global__ __launch_bounds__(256) void k_gemm(
    const float* __restrict__ in, const float* __restrict__ W,
    const float* __restrict__ bias, const float* __restrict__ scale,
    const float* __restrict__ shift, const float* __restrict__ dis,
    float* __restrict__ t_out, float* __restrict__ agg_out, int N) {
  constexpr int HSTR = BM + 4;  // 132: keeps 16B-aligned b128 reads, breaks read conflicts
  __shared__ float hT[KSTEP][HSTR];
  __shared__ float Wl[KSTEP][BNC];  // XOR-swizzled in 4-float groups

  const int tid = threadIdx.x;
  const int tx = tid & 15, ty = tid >> 4;
  const int rowBase = blockIdx.x * BM;
  const int r0 = ty * 8;
  const int j0 = tx * TN;

  float acc[8][TN];
#pragma unroll
  for (int m = 0; m < 8; ++m)
#pragma unroll
    for (int n = 0; n < TN; ++n) acc[m][n] = 0.f;

  const int kg = (tid & 7) * 4;  // k offset within chunk for staging
  const int rr = tid >> 3;       // row within 32-row staging pass

  for (int kc = 0; kc < KTOT; kc += KSTEP) {
    // ---- stage A^T (with optional BN+ReLU fused on load) ----
#pragma unroll
    for (int p = 0; p < 4; ++p) {
      const int row = rr + p * 32;
      const int grow = rowBase + row;
      float4 v = make_float4(0.f, 0.f, 0.f, 0.f);
      if (grow < N)
        v = *reinterpret_cast<const float4*>(in + (size_t)grow * KTOT + kc + kg);
      if constexpr (APPLY_BN) {
        v.x = fmaxf(fmaf(v.x, scale[kc + kg + 0], shift[kc + kg + 0]), 0.f);
        v.y = fmaxf(fmaf(v.y, scale[kc + kg + 1], shift[kc + kg + 1]), 0.f);
        v.z = fmaxf(fmaf(v.z, scale[kc + kg + 2], shift[kc + kg + 2]), 0.f);
        v.w = fmaxf(fmaf(v.w, scale[kc + kg + 3], shift[kc + kg + 3]), 0.f);
      }
      hT[kg + 0][row] = v.x;
      hT[kg + 1][row] = v.y;
      hT[kg + 2][row] = v.z;
      hT[kg + 3][row] = v.w;
    }
    // ---- stage W (swizzled) ----
#pragma unroll
    for (int p = 0; p < (KSTEP * BNC) / 1024; ++p) {
      int idx = (tid + p * 256) * 4;
      int k = idx / BNC, j = idx % BNC;
      int g = j >> 2;
      int gs = g ^ (g >> 3);
      float4 v = *reinterpret_cast<const float4*>(W + (size_t)(kc + k) * BNC + j);
      *reinterpret_cast<float4*>(&Wl[k][gs << 2]) = v;
    }
    __syncthreads();

    // ---- inner product ----
#pragma unroll 4
    for (int k = 0; k < KSTEP; ++k) {
      float a[8], b[TN];
      *reinterpret_cast<float4*>(&a[0]) = *reinterpret_cast<const float4*>(&hT[k][r0]);
      *reinterpret_cast<float4*>(&a[4]) = *reinterpret_cast<const float4*>(&hT[k][r0 + 4]);
#pragma unroll
      for (int n4 = 0; n4 < TN / 4; ++n4) {
        int g = (j0 >> 2) + n4;
        int gs = g ^ (g >> 3);
        *reinterpret_cast<float4*>(&b[n4 * 4]) =
            *reinterpret_cast<const float4*>(&Wl[k][gs << 2]);
      }
#pragma unroll
      for (int m = 0; m < 8; ++m)
#pragma unroll
        for (int n = 0; n < TN; ++n) acc[m][n] = fmaf(a[m], b[n], acc[m][n]);
    }
    __syncthreads();
  }

  // ---- epilogue ----
  float bj[TN];
#pragma unroll
  for (int n = 0; n < TN; ++n) bj[n] = bias[j0 + n];

#pragma unroll
  for (int m = 0; m < 8; ++m) {
    const int r = rowBase + r0 + m;
    if (r < N) {
      if constexpr (FINAL) {
        float o[TN];
#pragma unroll
        for (int n = 0; n < TN; ++n) o[n] = acc[m][n] + bj[n];
#pragma unroll
        for (int n4 = 0; n4 < TN / 4; ++n4)
          *reinterpret_cast<float4*>(agg_out + (size_t)r * BNC + j0 + n4 * 4) =
              *reinterpret_cast<const float4*>(&o[n4 * 4]);
      } else {
        float d = dis[r];
        float sc = d * d;  // self-loop coef = 1/deg
        float tv[TN], av[TN];
#pragma unroll
        for (int n = 0; n < TN; ++n) {
          tv[n] = acc[m][n];
          av[n] = fmaf(tv[n], sc, bj[n]);
        }
#pragma unroll
        for (int n4 = 0; n4 < TN / 4; ++n4) {
          *reinterpret_cast<float4*>(t_out + (size_t)r * BNC + j0 + n4 * 4) =
              *reinterpret_cast<const float4*>(&tv[n4 * 4]);
          *reinterpret_cast<float4*>(agg_out + (size_t)r * BNC + j0 + n4 * 4) =
              *reinterpret_cast<const float4*>(&av[n4 * 4]);
        }
      }
    }
  }
}

// ---------- edge scatter: agg[dst] += t[src] * coef ----------
__global__ __launch_bounds__(256) void k_edge(const int* __restrict__ src,
                                              const int* __restrict__ dst,
                                              const float* __restrict__ coef,
                                              const float* __restrict__ t,
                                              float* __restrict__ agg, int E) {
  const int lane = threadIdx.x & 31;
  const int sub = threadIdx.x >> 5;  // 8 edges per 256-thread block
  const long long e = (long long)blockIdx.x * 8 + sub;
  if (e >= E) return;
  const int s = src[e], d = dst[e];
  const float c = coef[e];
  float4 v = *reinterpret_cast<const float4*>(t + (size_t)s * 128 + lane * 4);
  float* ap = agg + (size_t)d * 128 + lane * 4;
  atomicAdd(ap + 0, v.x * c);
  atomicAdd(ap + 1, v.y * c);
  atomicAdd(ap + 2, v.z * c);
  atomicAdd(ap + 3, v.w * c);
}

// ---------- launch ----------
extern "C" void kernel_launch(void* const* d_in, const int* in_sizes, int n_in,
                              void* d_out, int out_size, void* d_ws, size_t ws_size,
                              hipStream_t stream) {
  const float* x      = (const float*)d_in[0];
  const int*   ei     = (const int*)d_in[1];
  const float* W_in   = (const float*)d_in[2];
  const float* b_in   = (const float*)d_in[3];
  const float* Ws     = (const float*)d_in[4];
  const float* bs     = (const float*)d_in[5];
  const float* gammas = (const float*)d_in[6];
  const float* betas  = (const float*)d_in[7];
  const float* mean   = (const float*)d_in[8];
  const float* var    = (const float*)d_in[9];
  const float* W_out  = (const float*)d_in[10];
  const float* b_out  = (const float*)d_in[11];
  float* out = (float*)d_out;

  const int N = in_sizes[0] / 128;
  const int E = in_sizes[1] / 2;
  const int* src = ei;
  const int* dst = ei + E;

  char* ws = (char*)d_ws;
  size_t off = 0;
  auto alloc = [&](size_t bytes) {
    void* p = ws + off;
    off = (off + bytes + 255) & ~255ULL;
    return p;
  };
  float* deg   = (float*)alloc((size_t)N * 4);
  float* dis   = (float*)alloc((size_t)N * 4);
  float* scale = (float*)alloc(5 * 128 * 4);
  float* shift = (float*)alloc(5 * 128 * 4);
  float* coef  = (float*)alloc((size_t)E * 4);
  float* t     = (float*)alloc((size_t)N * 128 * 4);
  float* aggA  = (float*)alloc((size_t)N * 128 * 4);
  float* aggB  = (float*)alloc((size_t)N * 128 * 4);
  (void)ws_size;

  hipMemsetAsync(deg, 0, (size_t)N * 4, stream);
  k_deg<<<(E + 255) / 256, 256, 0, stream>>>(dst, deg, E);
  k_dis<<<(N + 255) / 256, 256, 0, stream>>>(deg, dis, N);
  k_coef<<<(E + 255) / 256, 256, 0, stream>>>(src, dst, dis, coef, E);
  k_bnparam<<<(5 * 128 + 255) / 256, 256, 0, stream>>>(gammas, betas, mean, var,
                                                       scale, shift, 5 * 128);

  const int gblocks = (N + BM - 1) / BM;
  const float* cur_in = x;
  float* cur_agg = nullptr;
  for (int l = 0; l < 5; ++l) {
    const float* W = (l == 0) ? W_in : Ws + (size_t)(l - 1) * 128 * 128;
    const float* b = (l == 0) ? b_in : bs + (size_t)(l - 1) * 128;
    cur_agg = (l & 1) ? aggB : aggA;
    if (l == 0)
      k_gemm<128, 8, false, false><<<gblocks, 256, 0, stream>>>(
          cur_in, W, b, nullptr, nullptr, dis, t, cur_agg, N);
    else
      k_gemm<128, 8, true, false><<<gblocks, 256, 0, stream>>>(
          cur_in, W, b, scale + (l - 1) * 128, shift + (l - 1) * 128, dis, t,
          cur_agg, N);
    k_edge<<<(E + 7) / 8, 256, 0, stream>>>(src, dst, coef, t, cur_agg, E);
    cur_in = cur_agg;
  }
  k_gemm<64, 4, true, true><<<gblocks, 256, 0, stream>>>(
      cur_in, W_out, b_out, scale + 4 * 128, shift + 4 * 128, dis, nullptr, out, N);
}

// Round 2
// 689.286 us; speedup vs baseline: 8.3105x; 8.3105x over previous
//
#include <hip/hip_runtime.h>
#include <cstdint>

#define BN_EPS 1e-5f

constexpr int KTOT  = 128;   // K of every GEMM (input feature width)
constexpr int BM    = 128;   // rows per block
constexpr int KSTEP = 32;    // K chunk staged in LDS

// ---------- CSR build ----------

__global__ __launch_bounds__(256) void k_count(const int* __restrict__ dstv,
                                               int* __restrict__ counts, int E) {
  int e = blockIdx.x * 256 + threadIdx.x;
  if (e < E) atomicAdd(counts + dstv[e], 1);
}

__global__ __launch_bounds__(256) void k_dis(const int* __restrict__ counts,
                                             float* __restrict__ dis, int N) {
  int i = blockIdx.x * 256 + threadIdx.x;
  if (i < N) dis[i] = rsqrtf((float)counts[i] + 1.0f);
}

// per-block (1024 elems) exclusive scan; block total -> bsum
__global__ __launch_bounds__(256) void k_scan1(const int* __restrict__ counts,
                                               int* __restrict__ rowstart,
                                               int* __restrict__ bsum, int N) {
  __shared__ int wsum[4];
  const int tid = threadIdx.x, lane = tid & 63, wv = tid >> 6;
  const int base = blockIdx.x * 1024 + tid * 4;
  int c[4];
#pragma unroll
  for (int j = 0; j < 4; ++j) {
    int idx = base + j;
    c[j] = (idx < N) ? counts[idx] : 0;
  }
  int s = c[0] + c[1] + c[2] + c[3];
  int x = s;  // inclusive wave scan
  for (int d = 1; d < 64; d <<= 1) {
    int y = __shfl_up(x, d);
    if (lane >= d) x += y;
  }
  if (lane == 63) wsum[wv] = x;
  __syncthreads();
  int woff = 0;
  for (int w = 0; w < wv; ++w) woff += wsum[w];
  int r = woff + x - s;  // exclusive base for this thread's 4 elems
#pragma unroll
  for (int j = 0; j < 4; ++j) {
    int idx = base + j;
    if (idx < N) rowstart[idx] = r;
    r += c[j];
  }
  if (tid == 255) bsum[blockIdx.x] = woff + x;
}

// single-block exclusive scan of block sums (nb <= 256)
__global__ __launch_bounds__(256) void k_scan2(const int* __restrict__ bsum,
                                               int* __restrict__ boff, int nb) {
  __shared__ int sm[256];
  const int tid = threadIdx.x;
  int v = (tid < nb) ? bsum[tid] : 0;
  sm[tid] = v;
  __syncthreads();
  for (int d = 1; d < 256; d <<= 1) {
    int y = (tid >= d) ? sm[tid - d] : 0;
    __syncthreads();
    sm[tid] += y;
    __syncthreads();
  }
  if (tid < nb) boff[tid] = sm[tid] - v;
}

__global__ __launch_bounds__(256) void k_fix(int* __restrict__ rowstart,
                                             const int* __restrict__ boff,
                                             int* __restrict__ cursor, int N) {
  int i = blockIdx.x * 256 + threadIdx.x;
  if (i < N) {
    int v = rowstart[i] + boff[i >> 10];
    rowstart[i] = v;
    cursor[i] = v;
  }
}

__global__ __launch_bounds__(256) void k_scatter(const int* __restrict__ src,
                                                 const int* __restrict__ dstv,
                                                 const float* __restrict__ dis,
                                                 int* __restrict__ cursor,
                                                 int* __restrict__ esrc,
                                                 float* __restrict__ ecoef, int E) {
  int e = blockIdx.x * 256 + threadIdx.x;
  if (e < E) {
    int s = src[e], d = dstv[e];
    int p = atomicAdd(cursor + d, 1);
    esrc[p] = s;
    ecoef[p] = dis[s] * dis[d];
  }
}

__global__ __launch_bounds__(256) void k_bnparam(const float* __restrict__ gamma,
                                                 const float* __restrict__ beta,
                                                 const float* __restrict__ mean,
                                                 const float* __restrict__ var,
                                                 float* __restrict__ scale,
                                                 float* __restrict__ shift, int n) {
  int i = blockIdx.x * 256 + threadIdx.x;
  if (i < n) {
    float s = gamma[i] * rsqrtf(var[i] + BN_EPS);
    scale[i] = s;
    shift[i] = beta[i] - mean[i] * s;
  }
}

// ---------- fused GEMM ----------
// out tile: BM x BNC, block 16x16 threads, per-thread 8 x TN register tile.
// APPLY_BN: input is pre-BN agg; apply relu(in*scale+shift) on load.
// FINAL: write out = acc + bias. Else write t only (self/bias handled in k_agg).
template <int BNC, int TN, bool APPLY_BN, bool FINAL>
__global__ __launch_bounds__(256) void k_gemm(
    const float* __restrict__ in, const float* __restrict__ W,
    const float* __restrict__ bias, const float* __restrict__ scale,
    const float* __restrict__ shift, float* __restrict__ out_p, int N) {
  constexpr int HSTR = BM + 4;
  __shared__ float hT[KSTEP][HSTR];
  __shared__ float Wl[KSTEP][BNC];  // XOR-swizzled in 4-float groups

  const int tid = threadIdx.x;
  const int tx = tid & 15, ty = tid >> 4;
  const int rowBase = blockIdx.x * BM;
  const int r0 = ty * 8;
  const int j0 = tx * TN;

  float acc[8][TN];
#pragma unroll
  for (int m = 0; m < 8; ++m)
#pragma unroll
    for (int n = 0; n < TN; ++n) acc[m][n] = 0.f;

  const int kg = (tid & 7) * 4;
  const int rr = tid >> 3;

  for (int kc = 0; kc < KTOT; kc += KSTEP) {
#pragma unroll
    for (int p = 0; p < 4; ++p) {
      const int row = rr + p * 32;
      const int grow = rowBase + row;
      float4 v = make_float4(0.f, 0.f, 0.f, 0.f);
      if (grow < N)
        v = *reinterpret_cast<const float4*>(in + (size_t)grow * KTOT + kc + kg);
      if constexpr (APPLY_BN) {
        v.x = fmaxf(fmaf(v.x, scale[kc + kg + 0], shift[kc + kg + 0]), 0.f);
        v.y = fmaxf(fmaf(v.y, scale[kc + kg + 1], shift[kc + kg + 1]), 0.f);
        v.z = fmaxf(fmaf(v.z, scale[kc + kg + 2], shift[kc + kg + 2]), 0.f);
        v.w = fmaxf(fmaf(v.w, scale[kc + kg + 3], shift[kc + kg + 3]), 0.f);
      }
      hT[kg + 0][row] = v.x;
      hT[kg + 1][row] = v.y;
      hT[kg + 2][row] = v.z;
      hT[kg + 3][row] = v.w;
    }
#pragma unroll
    for (int p = 0; p < (KSTEP * BNC) / 1024; ++p) {
      int idx = (tid + p * 256) * 4;
      int k = idx / BNC, j = idx % BNC;
      int g = j >> 2;
      int gs = g ^ (g >> 3);
      float4 v = *reinterpret_cast<const float4*>(W + (size_t)(kc + k) * BNC + j);
      *reinterpret_cast<float4*>(&Wl[k][gs << 2]) = v;
    }
    __syncthreads();

#pragma unroll 4
    for (int k = 0; k < KSTEP; ++k) {
      float a[8], b[TN];
      *reinterpret_cast<float4*>(&a[0]) = *reinterpret_cast<const float4*>(&hT[k][r0]);
      *reinterpret_cast<float4*>(&a[4]) = *reinterpret_cast<const float4*>(&hT[k][r0 + 4]);
#pragma unroll
      for (int n4 = 0; n4 < TN / 4; ++n4) {
        int g = (j0 >> 2) + n4;
        int gs = g ^ (g >> 3);
        *reinterpret_cast<float4*>(&b[n4 * 4]) =
            *reinterpret_cast<const float4*>(&Wl[k][gs << 2]);
      }
#pragma unroll
      for (int m = 0; m < 8; ++m)
#pragma unroll
        for (int n = 0; n < TN; ++n) acc[m][n] = fmaf(a[m], b[n], acc[m][n]);
    }
    __syncthreads();
  }

  float bj[TN];
  if constexpr (FINAL) {
#pragma unroll
    for (int n = 0; n < TN; ++n) bj[n] = bias[j0 + n];
  }

#pragma unroll
  for (int m = 0; m < 8; ++m) {
    const int r = rowBase + r0 + m;
    if (r < N) {
      if constexpr (FINAL) {
        float o[TN];
#pragma unroll
        for (int n = 0; n < TN; ++n) o[n] = acc[m][n] + bj[n];
#pragma unroll
        for (int n4 = 0; n4 < TN / 4; ++n4)
          *reinterpret_cast<float4*>(out_p + (size_t)r * BNC + j0 + n4 * 4) =
              *reinterpret_cast<const float4*>(&o[n4 * 4]);
      } else {
#pragma unroll
        for (int n4 = 0; n4 < TN / 4; ++n4)
          *reinterpret_cast<float4*>(out_p + (size_t)r * BNC + j0 + n4 * 4) =
              *reinterpret_cast<const float4*>(&acc[m][n4 * 4]);
      }
    }
  }
}

// ---------- CSR gather: agg[d] = sum_e t[src_e]*coef_e + t[d]/deg + bias ----------
__global__ __launch_bounds__(256) void k_agg(const int* __restrict__ rowstart,
                                             const int* __restrict__ counts,
                                             const int* __restrict__ esrc,
                                             const float* __restrict__ ecoef,
                                             const float* __restrict__ t,
                                             const float* __restrict__ dis,
                                             const float* __restrict__ bias,
                                             float* __restrict__ agg, int N) {
  const int lane = threadIdx.x & 63;
  const int wv = threadIdx.x >> 6;
  const int node = blockIdx.x * 4 + wv;
  if (node >= N) return;
  const int beg = rowstart[node];
  const int cnt = counts[node];
  const float dsq = dis[node] * dis[node];

  float2 acc = *reinterpret_cast<const float2*>(t + (size_t)node * 128 + lane * 2);
  acc.x *= dsq;
  acc.y *= dsq;

  int i = 0;
  for (; i + 2 <= cnt; i += 2) {
    const int s0 = esrc[beg + i], s1 = esrc[beg + i + 1];
    const float c0 = ecoef[beg + i], c1 = ecoef[beg + i + 1];
    float2 v0 = *reinterpret_cast<const float2*>(t + (size_t)s0 * 128 + lane * 2);
    float2 v1 = *reinterpret_cast<const float2*>(t + (size_t)s1 * 128 + lane * 2);
    acc.x = fmaf(v0.x, c0, acc.x);
    acc.y = fmaf(v0.y, c0, acc.y);
    acc.x = fmaf(v1.x, c1, acc.x);
    acc.y = fmaf(v1.y, c1, acc.y);
  }
  if (i < cnt) {
    const int s0 = esrc[beg + i];
    const float c0 = ecoef[beg + i];
    float2 v0 = *reinterpret_cast<const float2*>(t + (size_t)s0 * 128 + lane * 2);
    acc.x = fmaf(v0.x, c0, acc.x);
    acc.y = fmaf(v0.y, c0, acc.y);
  }
  acc.x += bias[lane * 2 + 0];
  acc.y += bias[lane * 2 + 1];
  *reinterpret_cast<float2*>(agg + (size_t)node * 128 + lane * 2) = acc;
}

// ---------- launch ----------
extern "C" void kernel_launch(void* const* d_in, const int* in_sizes, int n_in,
                              void* d_out, int out_size, void* d_ws, size_t ws_size,
                              hipStream_t stream) {
  const float* x      = (const float*)d_in[0];
  const int*   ei     = (const int*)d_in[1];
  const float* W_in   = (const float*)d_in[2];
  const float* b_in   = (const float*)d_in[3];
  const float* Ws     = (const float*)d_in[4];
  const float* bs     = (const float*)d_in[5];
  const float* gammas = (const float*)d_in[6];
  const float* betas  = (const float*)d_in[7];
  const float* mean   = (const float*)d_in[8];
  const float* var    = (const float*)d_in[9];
  const float* W_out  = (const float*)d_in[10];
  const float* b_out  = (const float*)d_in[11];
  float* out = (float*)d_out;

  const int N = in_sizes[0] / 128;
  const int E = in_sizes[1] / 2;
  const int* src = ei;
  const int* dst = ei + E;

  char* ws = (char*)d_ws;
  size_t off = 0;
  auto alloc = [&](size_t bytes) {
    void* p = ws + off;
    off = (off + bytes + 255) & ~255ULL;
    return p;
  };
  int*   counts   = (int*)alloc((size_t)N * 4);
  int*   rowstart = (int*)alloc((size_t)N * 4);
  int*   cursor   = (int*)alloc((size_t)N * 4);
  int*   bsum     = (int*)alloc(256 * 4);
  int*   boff     = (int*)alloc(256 * 4);
  float* dis      = (float*)alloc((size_t)N * 4);
  float* scale    = (float*)alloc(5 * 128 * 4);
  float* shift    = (float*)alloc(5 * 128 * 4);
  int*   esrc     = (int*)alloc((size_t)E * 4);
  float* ecoef    = (float*)alloc((size_t)E * 4);
  float* t        = (float*)alloc((size_t)N * 128 * 4);
  float* agg      = (float*)alloc((size_t)N * 128 * 4);
  (void)ws_size;

  const int nb = (N + 1023) / 1024;  // scan blocks (<=256 supported)

  hipMemsetAsync(counts, 0, (size_t)N * 4, stream);
  k_count<<<(E + 255) / 256, 256, 0, stream>>>(dst, counts, E);
  k_dis<<<(N + 255) / 256, 256, 0, stream>>>(counts, dis, N);
  k_scan1<<<nb, 256, 0, stream>>>(counts, rowstart, bsum, N);
  k_scan2<<<1, 256, 0, stream>>>(bsum, boff, nb);
  k_fix<<<(N + 255) / 256, 256, 0, stream>>>(rowstart, boff, cursor, N);
  k_scatter<<<(E + 255) / 256, 256, 0, stream>>>(src, dst, dis, cursor, esrc, ecoef, E);
  k_bnparam<<<(5 * 128 + 255) / 256, 256, 0, stream>>>(gammas, betas, mean, var,
                                                       scale, shift, 5 * 128);

  const int gblocks = (N + BM - 1) / BM;
  const int ablocks = (N + 3) / 4;
  const float* cur_in = x;
  for (int l = 0; l < 5; ++l) {
    const float* W = (l == 0) ? W_in : Ws + (size_t)(l - 1) * 128 * 128;
    const float* b = (l == 0) ? b_in : bs + (size_t)(l - 1) * 128;
    if (l == 0)
      k_gemm<128, 8, false, false><<<gblocks, 256, 0, stream>>>(
          cur_in, W, b, nullptr, nullptr, t, N);
    else
      k_gemm<128, 8, true, false><<<gblocks, 256, 0, stream>>>(
          cur_in, W, b, scale + (l - 1) * 128, shift + (l - 1) * 128, t, N);
    k_agg<<<ablocks, 256, 0, stream>>>(rowstart, counts, esrc, ecoef, t, dis, b, agg, N);
    cur_in = agg;
  }
  k_gemm<64, 4, true, true><<<gblocks, 256, 0, stream>>>(
      cur_in, W_out, b_out, scale + 4 * 128, shift + 4 * 128, out, N);
}